// Round 1
// baseline (893.032 us; speedup 1.0000x reference)
//
#include <hip/hip_runtime.h>

// Problem constants: B=16, P=1024, E=1024, H=16, DH=64
#define PB 16
#define PP 1024
#define PE 1024
#define PH 16
#define PDH 64

typedef __attribute__((ext_vector_type(8))) short bf16x8;
typedef __attribute__((ext_vector_type(4))) short bf16x4;
typedef __attribute__((ext_vector_type(4))) float f32x4;

__device__ __forceinline__ short f2bf(float f) {
    union { float f; unsigned u; } a;
    a.f = f;
    unsigned u = a.u;
    u += 0x7fffu + ((u >> 16) & 1u);   // round-to-nearest-even
    return (short)(u >> 16);
}

// ---------------------------------------------------------------------------
// Kernel 1: xw[b,h,p,e'] = (x_h[b,h,p,:] @ w_att_val[h]) * 0.125  (bf16 out)
// x_h[b,h,p,d] == x[b, p, h*64+d] (contiguous d) -> read x directly.
// grid: B*H*4 blocks, 256 threads (4 waves); each block does 256 p-rows.
// ---------------------------------------------------------------------------
__global__ __launch_bounds__(256) void xw_kernel(const float* __restrict__ x,
                                                 const float* __restrict__ watt,
                                                 short* __restrict__ xw) {
    int bid = blockIdx.x;
    int q4 = bid & 3;
    int bh = bid >> 2;          // b*16 + h
    int h = bh & 15;
    __shared__ short Wt[64][88];   // W^T: Wt[e'][d], pad 88 (176B rows, 16B aligned)

    int tid = threadIdx.x;
    {   // stage W[h] transposed, fp32 -> bf16
        const float* W = watt + (size_t)h * 4096;  // [64 d][64 e'] row-major
        int idx = tid * 16;
        int d = idx >> 6, e0 = idx & 63;
#pragma unroll
        for (int i = 0; i < 16; i += 4) {
            float4 v = *(const float4*)(W + d * 64 + e0 + i);
            Wt[e0 + i + 0][d] = f2bf(v.x);
            Wt[e0 + i + 1][d] = f2bf(v.y);
            Wt[e0 + i + 2][d] = f2bf(v.z);
            Wt[e0 + i + 3][d] = f2bf(v.w);
        }
    }
    __syncthreads();

    int wave = tid >> 6, lane = tid & 63;
    int lm = lane & 15, lq = lane >> 4;

    // B-frags: B[k=d][n=e'] = W[d][e'] = Wt[e'][d], lane: n=lm, k=lq*8+j (+32*kf)
    bf16x8 bfr[4][2];
#pragma unroll
    for (int nt = 0; nt < 4; nt++)
#pragma unroll
        for (int kf = 0; kf < 2; kf++)
            bfr[nt][kf] = *(const bf16x8*)&Wt[nt * 16 + lm][kf * 32 + lq * 8];

    int b = bh >> 4;
    for (int pass = 0; pass < 4; pass++) {
        int p0 = q4 * 256 + pass * 64 + wave * 16;
        const float* xrow = x + ((size_t)(b * 1024 + p0 + lm)) * 1024 + h * 64;
        bf16x8 af[2];
#pragma unroll
        for (int kf = 0; kf < 2; kf++) {
            float4 v0 = *(const float4*)(xrow + kf * 32 + lq * 8);
            float4 v1 = *(const float4*)(xrow + kf * 32 + lq * 8 + 4);
            bf16x8 t;
            t[0] = f2bf(v0.x); t[1] = f2bf(v0.y); t[2] = f2bf(v0.z); t[3] = f2bf(v0.w);
            t[4] = f2bf(v1.x); t[5] = f2bf(v1.y); t[6] = f2bf(v1.z); t[7] = f2bf(v1.w);
            af[kf] = t;
        }
#pragma unroll
        for (int nt = 0; nt < 4; nt++) {
            f32x4 acc = {0.f, 0.f, 0.f, 0.f};
            acc = __builtin_amdgcn_mfma_f32_16x16x32_bf16(af[0], bfr[nt][0], acc, 0, 0, 0);
            acc = __builtin_amdgcn_mfma_f32_16x16x32_bf16(af[1], bfr[nt][1], acc, 0, 0, 0);
            size_t base = ((size_t)bh * 1024 + p0 + lq * 4) * 64 + nt * 16 + lm;
#pragma unroll
            for (int r = 0; r < 4; r++)
                xw[base + (size_t)r * 64] = f2bf(acc[r] * 0.125f);
        }
    }
}

// ---------------------------------------------------------------------------
// Kernel 2: vt[b,h,d,p] = (x @ wv_w^T + wv_b) transposed-split-heads (bf16)
// 128x128 tile, BK=32, 4 waves each 64x64.
// ---------------------------------------------------------------------------
__global__ __launch_bounds__(256) void vx_gemm(const float* __restrict__ x,
                                               const float* __restrict__ wvw,
                                               const float* __restrict__ wvb,
                                               short* __restrict__ vt) {
    int mblk = blockIdx.x >> 3, nblk = blockIdx.x & 7;
    int m0 = mblk * 128, n0 = nblk * 128;
    __shared__ short As[128][40];   // [m][k], 80B rows (16B aligned)
    __shared__ short Bs[128][40];   // [n][k] (wv_w row-major is already n-by-k)

    int tid = threadIdx.x;
    int srow = tid >> 1, sseg = (tid & 1) * 16;
    const float* ag = x + (size_t)(m0 + srow) * 1024 + sseg;
    const float* bg = wvw + (size_t)(n0 + srow) * 1024 + sseg;

    int wave = tid >> 6, lane = tid & 63, lm = lane & 15, lq = lane >> 4;
    int wm = (wave >> 1) * 64, wn = (wave & 1) * 64;

    f32x4 acc[4][4];
#pragma unroll
    for (int i = 0; i < 4; i++)
#pragma unroll
        for (int j = 0; j < 4; j++) acc[i][j] = (f32x4){0.f, 0.f, 0.f, 0.f};

    for (int k0 = 0; k0 < 1024; k0 += 32) {
        __syncthreads();
        {
            float4 a0 = *(const float4*)(ag + k0);
            float4 a1 = *(const float4*)(ag + k0 + 4);
            float4 a2 = *(const float4*)(ag + k0 + 8);
            float4 a3 = *(const float4*)(ag + k0 + 12);
            float4 b0 = *(const float4*)(bg + k0);
            float4 b1 = *(const float4*)(bg + k0 + 4);
            float4 b2 = *(const float4*)(bg + k0 + 8);
            float4 b3 = *(const float4*)(bg + k0 + 12);
            bf16x8 ta0 = {f2bf(a0.x), f2bf(a0.y), f2bf(a0.z), f2bf(a0.w),
                          f2bf(a1.x), f2bf(a1.y), f2bf(a1.z), f2bf(a1.w)};
            bf16x8 ta1 = {f2bf(a2.x), f2bf(a2.y), f2bf(a2.z), f2bf(a2.w),
                          f2bf(a3.x), f2bf(a3.y), f2bf(a3.z), f2bf(a3.w)};
            bf16x8 tb0 = {f2bf(b0.x), f2bf(b0.y), f2bf(b0.z), f2bf(b0.w),
                          f2bf(b1.x), f2bf(b1.y), f2bf(b1.z), f2bf(b1.w)};
            bf16x8 tb1 = {f2bf(b2.x), f2bf(b2.y), f2bf(b2.z), f2bf(b2.w),
                          f2bf(b3.x), f2bf(b3.y), f2bf(b3.z), f2bf(b3.w)};
            *(bf16x8*)&As[srow][sseg] = ta0;
            *(bf16x8*)&As[srow][sseg + 8] = ta1;
            *(bf16x8*)&Bs[srow][sseg] = tb0;
            *(bf16x8*)&Bs[srow][sseg + 8] = tb1;
        }
        __syncthreads();
        bf16x8 af[4], bfr[4];
#pragma unroll
        for (int mt = 0; mt < 4; mt++) af[mt] = *(const bf16x8*)&As[wm + mt * 16 + lm][lq * 8];
#pragma unroll
        for (int nt = 0; nt < 4; nt++) bfr[nt] = *(const bf16x8*)&Bs[wn + nt * 16 + lm][lq * 8];
#pragma unroll
        for (int mt = 0; mt < 4; mt++)
#pragma unroll
            for (int nt = 0; nt < 4; nt++)
                acc[mt][nt] = __builtin_amdgcn_mfma_f32_16x16x32_bf16(af[mt], bfr[nt], acc[mt][nt], 0, 0, 0);
    }

    // epilogue: +wv_b, bf16, scatter into vt[b][h][d][p] (4 consecutive p per lane -> 8B store)
#pragma unroll
    for (int nt = 0; nt < 4; nt++) {
        int e = n0 + wn + nt * 16 + lm;
        float bias = wvb[e];
        int hh = e >> 6, dd = e & 63;
#pragma unroll
        for (int mt = 0; mt < 4; mt++) {
            int pg = m0 + wm + mt * 16 + lq * 4;
            int bb = pg >> 10, pp = pg & 1023;
            bf16x4 pk;
#pragma unroll
            for (int r = 0; r < 4; r++) pk[r] = f2bf(acc[mt][nt][r] + bias);
            *(bf16x4*)(vt + ((size_t)((bb * 16 + hh) * 64 + dd)) * 1024 + pp) = pk;
        }
    }
}

// ---------------------------------------------------------------------------
// Kernel 3: flash attention. block = (b,h,q-tile of 128), 4 waves x 32 q-rows.
// KV tiles of 64. Q (=xw, pre-scaled) frags from global; K staged from x;
// V staged from vt (transposed layout -> contiguous B-frag reads).
// ---------------------------------------------------------------------------
__global__ __launch_bounds__(256) void flash_kernel(const float* __restrict__ x,
                                                    const short* __restrict__ xw,
                                                    const short* __restrict__ vt,
                                                    const float* __restrict__ bias,
                                                    short* __restrict__ obuf) {
    int bid = blockIdx.x;
    int qblk = bid & 7, bh = bid >> 3;
    int h = bh & 15, bb = bh >> 4;
    int q0 = qblk * 128;

    __shared__ short Ks[64][88];       // K[kv][d]
    __shared__ short Vs[64][88];       // V^T[d][kv]
    __shared__ short Ps[4][32][88];    // per-wave P repack (C/D -> A layout)

    int tid = threadIdx.x, wave = tid >> 6, lane = tid & 63;
    int lm = lane & 15, lq = lane >> 4;

    // Q A-frags: 32 rows x 64 d per wave
    bf16x8 qa[2][2];
#pragma unroll
    for (int mt = 0; mt < 2; mt++)
#pragma unroll
        for (int kf = 0; kf < 2; kf++)
            qa[mt][kf] = *(const bf16x8*)(xw + ((size_t)bh * 1024 + q0 + wave * 32 + mt * 16 + lm) * 64 + kf * 32 + lq * 8);

    f32x4 o[2][4];
#pragma unroll
    for (int mt = 0; mt < 2; mt++)
#pragma unroll
        for (int dt = 0; dt < 4; dt++) o[mt][dt] = (f32x4){0.f, 0.f, 0.f, 0.f};
    float m_i[2][4], l_i[2][4];
#pragma unroll
    for (int mt = 0; mt < 2; mt++)
#pragma unroll
        for (int r = 0; r < 4; r++) { m_i[mt][r] = -1e30f; l_i[mt][r] = 0.f; }

    const float* bias_h = bias + (size_t)h * 1024 * 1024;
    int krow = tid >> 2, kcs = (tid & 3) * 16;
    const float* kg0 = x + ((size_t)(bb * 1024) + krow) * 1024 + h * 64 + kcs;

    for (int kv0 = 0; kv0 < 1024; kv0 += 64) {
        __syncthreads();
        {   // stage K tile (fp32 -> bf16)
            const float* kg = kg0 + (size_t)kv0 * 1024;
            float4 v0 = *(const float4*)(kg);
            float4 v1 = *(const float4*)(kg + 4);
            float4 v2 = *(const float4*)(kg + 8);
            float4 v3 = *(const float4*)(kg + 12);
            bf16x8 t0 = {f2bf(v0.x), f2bf(v0.y), f2bf(v0.z), f2bf(v0.w),
                         f2bf(v1.x), f2bf(v1.y), f2bf(v1.z), f2bf(v1.w)};
            bf16x8 t1 = {f2bf(v2.x), f2bf(v2.y), f2bf(v2.z), f2bf(v2.w),
                         f2bf(v3.x), f2bf(v3.y), f2bf(v3.z), f2bf(v3.w)};
            *(bf16x8*)&Ks[krow][kcs] = t0;
            *(bf16x8*)&Ks[krow][kcs + 8] = t1;
        }
        {   // stage V tile (already bf16, already transposed)
#pragma unroll
            for (int i = 0; i < 2; i++) {
                int ci = tid * 2 + i;
                int r = ci >> 3, c = (ci & 7) * 8;
                bf16x8 v = *(const bf16x8*)(vt + ((size_t)bh * 64 + r) * 1024 + kv0 + c);
                *(bf16x8*)&Vs[r][c] = v;
            }
        }
        __syncthreads();

        // S = Q K^T  (Q pre-scaled by 0.125)
        f32x4 s[2][4];
#pragma unroll
        for (int kf = 0; kf < 2; kf++) {
            bf16x8 kb[4];
#pragma unroll
            for (int nt = 0; nt < 4; nt++)
                kb[nt] = *(const bf16x8*)&Ks[nt * 16 + lm][kf * 32 + lq * 8];
#pragma unroll
            for (int mt = 0; mt < 2; mt++)
#pragma unroll
                for (int nt = 0; nt < 4; nt++) {
                    if (kf == 0) s[mt][nt] = (f32x4){0.f, 0.f, 0.f, 0.f};
                    s[mt][nt] = __builtin_amdgcn_mfma_f32_16x16x32_bf16(qa[mt][kf], kb[nt], s[mt][nt], 0, 0, 0);
                }
        }

        // bias + online softmax (per m-tile; rows live in (lq, reg))
#pragma unroll
        for (int mt = 0; mt < 2; mt++) {
            int qrow = q0 + wave * 32 + mt * 16 + lq * 4;
#pragma unroll
            for (int nt = 0; nt < 4; nt++) {
                const float* bp = bias_h + (size_t)qrow * 1024 + kv0 + nt * 16 + lm;
#pragma unroll
                for (int r = 0; r < 4; r++) s[mt][nt][r] += bp[(size_t)r * 1024];
            }
            float mn[4], alpha[4], rs[4];
#pragma unroll
            for (int r = 0; r < 4; r++) {
                float v = fmaxf(fmaxf(s[mt][0][r], s[mt][1][r]), fmaxf(s[mt][2][r], s[mt][3][r]));
                v = fmaxf(v, __shfl_xor(v, 1));
                v = fmaxf(v, __shfl_xor(v, 2));
                v = fmaxf(v, __shfl_xor(v, 4));
                v = fmaxf(v, __shfl_xor(v, 8));
                mn[r] = fmaxf(m_i[mt][r], v);
                alpha[r] = exp2f((m_i[mt][r] - mn[r]) * 1.44269504089f);
                m_i[mt][r] = mn[r];
                rs[r] = 0.f;
            }
#pragma unroll
            for (int nt = 0; nt < 4; nt++)
#pragma unroll
                for (int r = 0; r < 4; r++) {
                    float pv = exp2f((s[mt][nt][r] - mn[r]) * 1.44269504089f);
                    s[mt][nt][r] = pv;
                    rs[r] += pv;
                }
#pragma unroll
            for (int r = 0; r < 4; r++) {
                float t = rs[r];
                t += __shfl_xor(t, 1);
                t += __shfl_xor(t, 2);
                t += __shfl_xor(t, 4);
                t += __shfl_xor(t, 8);
                l_i[mt][r] = l_i[mt][r] * alpha[r] + t;
            }
#pragma unroll
            for (int dt = 0; dt < 4; dt++)
#pragma unroll
                for (int r = 0; r < 4; r++) o[mt][dt][r] *= alpha[r];
            // P (C/D layout) -> wave-private LDS for A-layout reads
#pragma unroll
            for (int nt = 0; nt < 4; nt++)
#pragma unroll
                for (int r = 0; r < 4; r++)
                    Ps[wave][mt * 16 + lq * 4 + r][nt * 16 + lm] = f2bf(s[mt][nt][r]);
        }

        // O += P V
#pragma unroll
        for (int kf = 0; kf < 2; kf++) {
            bf16x8 pa[2], vb[4];
#pragma unroll
            for (int mt = 0; mt < 2; mt++)
                pa[mt] = *(const bf16x8*)&Ps[wave][mt * 16 + lm][kf * 32 + lq * 8];
#pragma unroll
            for (int dt = 0; dt < 4; dt++)
                vb[dt] = *(const bf16x8*)&Vs[dt * 16 + lm][kf * 32 + lq * 8];
#pragma unroll
            for (int mt = 0; mt < 2; mt++)
#pragma unroll
                for (int dt = 0; dt < 4; dt++)
                    o[mt][dt] = __builtin_amdgcn_mfma_f32_16x16x32_bf16(pa[mt], vb[dt], o[mt][dt], 0, 0, 0);
        }
    }

    // epilogue: O /= l, write obuf[b,p,e] bf16
#pragma unroll
    for (int mt = 0; mt < 2; mt++) {
        float inv[4];
#pragma unroll
        for (int r = 0; r < 4; r++) inv[r] = 1.f / l_i[mt][r];
#pragma unroll
        for (int dt = 0; dt < 4; dt++) {
            int e = h * 64 + dt * 16 + lm;
#pragma unroll
            for (int r = 0; r < 4; r++) {
                int p = q0 + wave * 32 + mt * 16 + lq * 4 + r;
                obuf[((size_t)(bb * 1024 + p)) * 1024 + e] = f2bf(o[mt][dt][r] * inv[r]);
            }
        }
    }
}

// ---------------------------------------------------------------------------
// Kernel 4: out = obuf @ out_w^T + out_b  (fp32 out)
// ---------------------------------------------------------------------------
__global__ __launch_bounds__(256) void out_gemm(const short* __restrict__ obuf,
                                                const float* __restrict__ outw,
                                                const float* __restrict__ outb,
                                                float* __restrict__ out) {
    int mblk = blockIdx.x >> 3, nblk = blockIdx.x & 7;
    int m0 = mblk * 128, n0 = nblk * 128;
    __shared__ short As[128][40];
    __shared__ short Bs[128][40];

    int tid = threadIdx.x;
    int srow = tid >> 1, sseg = (tid & 1) * 16;
    const short* ag = obuf + (size_t)(m0 + srow) * 1024 + sseg;
    const float* bg = outw + (size_t)(n0 + srow) * 1024 + sseg;

    int wave = tid >> 6, lane = tid & 63, lm = lane & 15, lq = lane >> 4;
    int wm = (wave >> 1) * 64, wn = (wave & 1) * 64;

    f32x4 acc[4][4];
#pragma unroll
    for (int i = 0; i < 4; i++)
#pragma unroll
        for (int j = 0; j < 4; j++) acc[i][j] = (f32x4){0.f, 0.f, 0.f, 0.f};

    for (int k0 = 0; k0 < 1024; k0 += 32) {
        __syncthreads();
        {
            bf16x8 ta0 = *(const bf16x8*)(ag + k0);
            bf16x8 ta1 = *(const bf16x8*)(ag + k0 + 8);
            float4 b0 = *(const float4*)(bg + k0);
            float4 b1 = *(const float4*)(bg + k0 + 4);
            float4 b2 = *(const float4*)(bg + k0 + 8);
            float4 b3 = *(const float4*)(bg + k0 + 12);
            bf16x8 tb0 = {f2bf(b0.x), f2bf(b0.y), f2bf(b0.z), f2bf(b0.w),
                          f2bf(b1.x), f2bf(b1.y), f2bf(b1.z), f2bf(b1.w)};
            bf16x8 tb1 = {f2bf(b2.x), f2bf(b2.y), f2bf(b2.z), f2bf(b2.w),
                          f2bf(b3.x), f2bf(b3.y), f2bf(b3.z), f2bf(b3.w)};
            *(bf16x8*)&As[srow][sseg] = ta0;
            *(bf16x8*)&As[srow][sseg + 8] = ta1;
            *(bf16x8*)&Bs[srow][sseg] = tb0;
            *(bf16x8*)&Bs[srow][sseg + 8] = tb1;
        }
        __syncthreads();
        bf16x8 af[4], bfr[4];
#pragma unroll
        for (int mt = 0; mt < 4; mt++) af[mt] = *(const bf16x8*)&As[wm + mt * 16 + lm][lq * 8];
#pragma unroll
        for (int nt = 0; nt < 4; nt++) bfr[nt] = *(const bf16x8*)&Bs[wn + nt * 16 + lm][lq * 8];
#pragma unroll
        for (int mt = 0; mt < 4; mt++)
#pragma unroll
            for (int nt = 0; nt < 4; nt++)
                acc[mt][nt] = __builtin_amdgcn_mfma_f32_16x16x32_bf16(af[mt], bfr[nt], acc[mt][nt], 0, 0, 0);
    }

#pragma unroll
    for (int nt = 0; nt < 4; nt++) {
        int e = n0 + wn + nt * 16 + lm;
        float bias = outb[e];
#pragma unroll
        for (int mt = 0; mt < 4; mt++) {
            int pg = m0 + wm + mt * 16 + lq * 4;
#pragma unroll
            for (int r = 0; r < 4; r++)
                out[(size_t)(pg + r) * 1024 + e] = acc[mt][nt][r] + bias;
        }
    }
}

extern "C" void kernel_launch(void* const* d_in, const int* in_sizes, int n_in,
                              void* d_out, int out_size, void* d_ws, size_t ws_size,
                              hipStream_t stream) {
    const float* x    = (const float*)d_in[0];  // [16,1024,1024]
    const float* watt = (const float*)d_in[1];  // [16,64,64]
    const float* bias = (const float*)d_in[2];  // [16,1024,1024]
    const float* wvw  = (const float*)d_in[3];  // [1024,1024]
    const float* wvb  = (const float*)d_in[4];  // [1024]
    const float* outw = (const float*)d_in[5];  // [1024,1024]
    const float* outb = (const float*)d_in[6];  // [1024]
    float* out = (float*)d_out;

    char* ws = (char*)d_ws;
    short* xw   = (short*)ws;                           // 32 MB  [B,H,P,DH] bf16 (Q, pre-scaled)
    short* vt   = (short*)(ws + ((size_t)32 << 20));    // 32 MB  [B,H,DH,P] bf16 (V^T)
    short* obuf = (short*)(ws + ((size_t)64 << 20));    // 32 MB  [B,P,E]    bf16 (attn out)

    xw_kernel<<<PB * PH * 4, 256, 0, stream>>>(x, watt, xw);
    vx_gemm<<<(PB * PP / 128) * (PE / 128), 256, 0, stream>>>(x, wvw, wvb, vt);
    flash_kernel<<<PB * PH * (PP / 128), 256, 0, stream>>>(x, xw, vt, bias, obuf);
    out_gemm<<<(PB * PP / 128) * (PE / 128), 256, 0, stream>>>(obuf, outw, outb, out);
}

// Round 2
// 661.749 us; speedup vs baseline: 1.3495x; 1.3495x over previous
//
#include <hip/hip_runtime.h>

// Problem constants: B=16, P=1024, E=1024, H=16, DH=64
#define PB 16
#define PP 1024
#define PE 1024
#define PH 16
#define PDH 64

typedef __attribute__((ext_vector_type(8))) short bf16x8;
typedef __attribute__((ext_vector_type(4))) short bf16x4;
typedef __attribute__((ext_vector_type(4))) float f32x4;

__device__ __forceinline__ short f2bf(float f) {
    union { float f; unsigned u; } a;
    a.f = f;
    unsigned u = a.u;
    u += 0x7fffu + ((u >> 16) & 1u);   // round-to-nearest-even
    return (short)(u >> 16);
}

// ---------------------------------------------------------------------------
// Kernel 0: biasT[h][kv][q] = bias[h][q][kv]  (fp32 transpose per head)
// grid: 16 h * 32*32 tiles of 32x32; 256 threads.
// ---------------------------------------------------------------------------
__global__ __launch_bounds__(256) void bias_prep(const float* __restrict__ bias,
                                                 float* __restrict__ biasT) {
    int bid = blockIdx.x;
    int h = bid >> 10;
    int t = bid & 1023;
    int qt = (t >> 5) * 32, kt = (t & 31) * 32;
    __shared__ float tl[32][33];
    int tid = threadIdx.x;
    int r = tid >> 3, c4 = (tid & 7) * 4;
    const float* src = bias + ((size_t)h << 20) + (size_t)(qt + r) * 1024 + kt + c4;
    float4 v = *(const float4*)src;
    tl[r][c4 + 0] = v.x; tl[r][c4 + 1] = v.y; tl[r][c4 + 2] = v.z; tl[r][c4 + 3] = v.w;
    __syncthreads();
    float4 w = {tl[c4 + 0][r], tl[c4 + 1][r], tl[c4 + 2][r], tl[c4 + 3][r]};
    *(float4*)(biasT + ((size_t)h << 20) + (size_t)(kt + r) * 1024 + qt + c4) = w;
}

// ---------------------------------------------------------------------------
// Kernel 1: xw[b,h,p,e'] = (x_h[b,h,p,:] @ w_att_val[h]) * 0.125  (bf16 out)
// ---------------------------------------------------------------------------
__global__ __launch_bounds__(256) void xw_kernel(const float* __restrict__ x,
                                                 const float* __restrict__ watt,
                                                 short* __restrict__ xw) {
    int bid = blockIdx.x;
    int q4 = bid & 3;
    int bh = bid >> 2;          // b*16 + h
    int h = bh & 15;
    __shared__ short Wt[64][88];   // W^T: Wt[e'][d]

    int tid = threadIdx.x;
    {   // stage W[h] transposed, fp32 -> bf16
        const float* W = watt + (size_t)h * 4096;  // [64 d][64 e'] row-major
        int idx = tid * 16;
        int d = idx >> 6, e0 = idx & 63;
#pragma unroll
        for (int i = 0; i < 16; i += 4) {
            float4 v = *(const float4*)(W + d * 64 + e0 + i);
            Wt[e0 + i + 0][d] = f2bf(v.x);
            Wt[e0 + i + 1][d] = f2bf(v.y);
            Wt[e0 + i + 2][d] = f2bf(v.z);
            Wt[e0 + i + 3][d] = f2bf(v.w);
        }
    }
    __syncthreads();

    int wave = tid >> 6, lane = tid & 63;
    int lm = lane & 15, lq = lane >> 4;

    bf16x8 bfr[4][2];
#pragma unroll
    for (int nt = 0; nt < 4; nt++)
#pragma unroll
        for (int kf = 0; kf < 2; kf++)
            bfr[nt][kf] = *(const bf16x8*)&Wt[nt * 16 + lm][kf * 32 + lq * 8];

    int b = bh >> 4;
    for (int pass = 0; pass < 4; pass++) {
        int p0 = q4 * 256 + pass * 64 + wave * 16;
        const float* xrow = x + ((size_t)(b * 1024 + p0 + lm)) * 1024 + h * 64;
        bf16x8 af[2];
#pragma unroll
        for (int kf = 0; kf < 2; kf++) {
            float4 v0 = *(const float4*)(xrow + kf * 32 + lq * 8);
            float4 v1 = *(const float4*)(xrow + kf * 32 + lq * 8 + 4);
            bf16x8 t;
            t[0] = f2bf(v0.x); t[1] = f2bf(v0.y); t[2] = f2bf(v0.z); t[3] = f2bf(v0.w);
            t[4] = f2bf(v1.x); t[5] = f2bf(v1.y); t[6] = f2bf(v1.z); t[7] = f2bf(v1.w);
            af[kf] = t;
        }
#pragma unroll
        for (int nt = 0; nt < 4; nt++) {
            f32x4 acc = {0.f, 0.f, 0.f, 0.f};
            acc = __builtin_amdgcn_mfma_f32_16x16x32_bf16(af[0], bfr[nt][0], acc, 0, 0, 0);
            acc = __builtin_amdgcn_mfma_f32_16x16x32_bf16(af[1], bfr[nt][1], acc, 0, 0, 0);
            size_t base = ((size_t)bh * 1024 + p0 + lq * 4) * 64 + nt * 16 + lm;
#pragma unroll
            for (int r = 0; r < 4; r++)
                xw[base + (size_t)r * 64] = f2bf(acc[r] * 0.125f);
        }
    }
}

// ---------------------------------------------------------------------------
// Kernel 2: vt[b,h,d,p] = (x @ wv_w^T + wv_b) transposed-split-heads (bf16)
// ---------------------------------------------------------------------------
__global__ __launch_bounds__(256) void vx_gemm(const float* __restrict__ x,
                                               const float* __restrict__ wvw,
                                               const float* __restrict__ wvb,
                                               short* __restrict__ vt) {
    int mblk = blockIdx.x >> 3, nblk = blockIdx.x & 7;
    int m0 = mblk * 128, n0 = nblk * 128;
    __shared__ short As[128][40];
    __shared__ short Bs[128][40];

    int tid = threadIdx.x;
    int srow = tid >> 1, sseg = (tid & 1) * 16;
    const float* ag = x + (size_t)(m0 + srow) * 1024 + sseg;
    const float* bg = wvw + (size_t)(n0 + srow) * 1024 + sseg;

    int wave = tid >> 6, lane = tid & 63, lm = lane & 15, lq = lane >> 4;
    int wm = (wave >> 1) * 64, wn = (wave & 1) * 64;

    f32x4 acc[4][4];
#pragma unroll
    for (int i = 0; i < 4; i++)
#pragma unroll
        for (int j = 0; j < 4; j++) acc[i][j] = (f32x4){0.f, 0.f, 0.f, 0.f};

    for (int k0 = 0; k0 < 1024; k0 += 32) {
        __syncthreads();
        {
            float4 a0 = *(const float4*)(ag + k0);
            float4 a1 = *(const float4*)(ag + k0 + 4);
            float4 a2 = *(const float4*)(ag + k0 + 8);
            float4 a3 = *(const float4*)(ag + k0 + 12);
            float4 b0 = *(const float4*)(bg + k0);
            float4 b1 = *(const float4*)(bg + k0 + 4);
            float4 b2 = *(const float4*)(bg + k0 + 8);
            float4 b3 = *(const float4*)(bg + k0 + 12);
            bf16x8 ta0 = {f2bf(a0.x), f2bf(a0.y), f2bf(a0.z), f2bf(a0.w),
                          f2bf(a1.x), f2bf(a1.y), f2bf(a1.z), f2bf(a1.w)};
            bf16x8 ta1 = {f2bf(a2.x), f2bf(a2.y), f2bf(a2.z), f2bf(a2.w),
                          f2bf(a3.x), f2bf(a3.y), f2bf(a3.z), f2bf(a3.w)};
            bf16x8 tb0 = {f2bf(b0.x), f2bf(b0.y), f2bf(b0.z), f2bf(b0.w),
                          f2bf(b1.x), f2bf(b1.y), f2bf(b1.z), f2bf(b1.w)};
            bf16x8 tb1 = {f2bf(b2.x), f2bf(b2.y), f2bf(b2.z), f2bf(b2.w),
                          f2bf(b3.x), f2bf(b3.y), f2bf(b3.z), f2bf(b3.w)};
            *(bf16x8*)&As[srow][sseg] = ta0;
            *(bf16x8*)&As[srow][sseg + 8] = ta1;
            *(bf16x8*)&Bs[srow][sseg] = tb0;
            *(bf16x8*)&Bs[srow][sseg + 8] = tb1;
        }
        __syncthreads();
        bf16x8 af[4], bfr[4];
#pragma unroll
        for (int mt = 0; mt < 4; mt++) af[mt] = *(const bf16x8*)&As[wm + mt * 16 + lm][lq * 8];
#pragma unroll
        for (int nt = 0; nt < 4; nt++) bfr[nt] = *(const bf16x8*)&Bs[wn + nt * 16 + lm][lq * 8];
#pragma unroll
        for (int mt = 0; mt < 4; mt++)
#pragma unroll
            for (int nt = 0; nt < 4; nt++)
                acc[mt][nt] = __builtin_amdgcn_mfma_f32_16x16x32_bf16(af[mt], bfr[nt], acc[mt][nt], 0, 0, 0);
    }

#pragma unroll
    for (int nt = 0; nt < 4; nt++) {
        int e = n0 + wn + nt * 16 + lm;
        float bias = wvb[e];
        int hh = e >> 6, dd = e & 63;
#pragma unroll
        for (int mt = 0; mt < 4; mt++) {
            int pg = m0 + wm + mt * 16 + lq * 4;
            int bb = pg >> 10, pp = pg & 1023;
            bf16x4 pk;
#pragma unroll
            for (int r = 0; r < 4; r++) pk[r] = f2bf(acc[mt][nt][r] + bias);
            *(bf16x4*)(vt + ((size_t)((bb * 16 + hh) * 64 + dd)) * 1024 + pp) = pk;
        }
    }
}

// ---------------------------------------------------------------------------
// Kernel 3: flash attention v2.
//  - bias folded into MFMA acc init via transposed biasT (vector loads)
//  - fixed-max softmax (no running max / alpha / O-rescale)
//  - register prefetch of next K/V tile; LDS 36.9KB -> 4 blocks/CU
// ---------------------------------------------------------------------------
__global__ __launch_bounds__(256, 4) void flash_kernel(const float* __restrict__ x,
                                                       const short* __restrict__ xw,
                                                       const short* __restrict__ vt,
                                                       const float* __restrict__ biasT,
                                                       short* __restrict__ obuf) {
    int bid = blockIdx.x;
    int qblk = bid & 7, bh = bid >> 3;
    int h = bh & 15, bb = bh >> 4;
    int q0 = qblk * 128;

    __shared__ short Ks[64][72];       // K[kv][d]
    __shared__ short Vs[64][72];       // V^T[d][kv]
    __shared__ short Ps[4][32][72];    // per-wave P (A layout)

    int tid = threadIdx.x, wave = tid >> 6, lane = tid & 63;
    int lm = lane & 15, lq = lane >> 4;

    // Q A-frags: 32 rows x 64 d per wave (pre-scaled by 0.125 in xw)
    bf16x8 qa[2][2];
#pragma unroll
    for (int mt = 0; mt < 2; mt++)
#pragma unroll
        for (int kf = 0; kf < 2; kf++)
            qa[mt][kf] = *(const bf16x8*)(xw + ((size_t)bh * 1024 + q0 + wave * 32 + mt * 16 + lm) * 64 + kf * 32 + lq * 8);

    f32x4 o[2][4];
#pragma unroll
    for (int mt = 0; mt < 2; mt++)
#pragma unroll
        for (int dt = 0; dt < 4; dt++) o[mt][dt] = (f32x4){0.f, 0.f, 0.f, 0.f};
    float rs[2][4];
#pragma unroll
    for (int mt = 0; mt < 2; mt++)
#pragma unroll
        for (int r = 0; r < 4; r++) rs[mt][r] = 0.f;

    // staging maps
    int krow = tid >> 2, kcs = (tid & 3) * 16;
    const float* kg0 = x + ((size_t)(bb * 1024) + krow) * 1024 + h * 64 + kcs;
    int vrow = (tid * 2) >> 3, vcol = ((tid * 2) & 7) * 8;   // thread handles rows vrow, cols vcol (2 x bf16x8)
    const short* vg0 = vt + ((size_t)bh * 64 + vrow) * 1024 + vcol;

    const float* bT = biasT + ((size_t)h << 20) + q0 + wave * 32;

    // prefetch tile 0
    float4 kr[4];
    bf16x8 vr[2];
    {
        kr[0] = *(const float4*)(kg0);
        kr[1] = *(const float4*)(kg0 + 4);
        kr[2] = *(const float4*)(kg0 + 8);
        kr[3] = *(const float4*)(kg0 + 12);
        vr[0] = *(const bf16x8*)(vg0);
        vr[1] = *(const bf16x8*)(vg0 + 1024 * 4);   // second row chunk: rows interleave by 4
    }
    // NOTE: the V mapping above must match the write below; recompute cleanly:
    // thread stages 2 bf16x8: chunk i at ci = tid*2+i -> row ci>>3, col (ci&7)*8
    // vr[i] loaded from vt row (ci>>3), col kv0+(ci&7)*8.
    {
        int ci0 = tid * 2, ci1 = tid * 2 + 1;
        vr[0] = *(const bf16x8*)(vt + ((size_t)bh * 64 + (ci0 >> 3)) * 1024 + ((ci0 & 7) * 8));
        vr[1] = *(const bf16x8*)(vt + ((size_t)bh * 64 + (ci1 >> 3)) * 1024 + ((ci1 & 7) * 8));
    }
    // write tile 0 to LDS
    {
        bf16x8 t0 = {f2bf(kr[0].x), f2bf(kr[0].y), f2bf(kr[0].z), f2bf(kr[0].w),
                     f2bf(kr[1].x), f2bf(kr[1].y), f2bf(kr[1].z), f2bf(kr[1].w)};
        bf16x8 t1 = {f2bf(kr[2].x), f2bf(kr[2].y), f2bf(kr[2].z), f2bf(kr[2].w),
                     f2bf(kr[3].x), f2bf(kr[3].y), f2bf(kr[3].z), f2bf(kr[3].w)};
        *(bf16x8*)&Ks[krow][kcs] = t0;
        *(bf16x8*)&Ks[krow][kcs + 8] = t1;
        int ci0 = tid * 2, ci1 = tid * 2 + 1;
        *(bf16x8*)&Vs[ci0 >> 3][(ci0 & 7) * 8] = vr[0];
        *(bf16x8*)&Vs[ci1 >> 3][(ci1 & 7) * 8] = vr[1];
    }

    for (int tile = 0; tile < 16; tile++) {
        int kv0 = tile * 64;
        __syncthreads();

        // prefetch next tile into regs (overlaps this tile's compute)
        if (tile < 15) {
            const float* kg = kg0 + (size_t)(kv0 + 64) * 1024;
            kr[0] = *(const float4*)(kg);
            kr[1] = *(const float4*)(kg + 4);
            kr[2] = *(const float4*)(kg + 8);
            kr[3] = *(const float4*)(kg + 12);
            int ci0 = tid * 2, ci1 = tid * 2 + 1;
            vr[0] = *(const bf16x8*)(vt + ((size_t)bh * 64 + (ci0 >> 3)) * 1024 + kv0 + 64 + ((ci0 & 7) * 8));
            vr[1] = *(const bf16x8*)(vt + ((size_t)bh * 64 + (ci1 >> 3)) * 1024 + kv0 + 64 + ((ci1 & 7) * 8));
        }

        // acc init from biasT (vectorized: 4 consecutive q per lane)
        f32x4 s[2][4];
#pragma unroll
        for (int mt = 0; mt < 2; mt++)
#pragma unroll
            for (int nt = 0; nt < 4; nt++)
                s[mt][nt] = *(const f32x4*)(bT + (size_t)(kv0 + nt * 16 + lm) * 1024 + mt * 16 + lq * 4);

        // S = Q K^T + bias
#pragma unroll
        for (int kf = 0; kf < 2; kf++) {
            bf16x8 kb[4];
#pragma unroll
            for (int nt = 0; nt < 4; nt++)
                kb[nt] = *(const bf16x8*)&Ks[nt * 16 + lm][kf * 32 + lq * 8];
#pragma unroll
            for (int mt = 0; mt < 2; mt++)
#pragma unroll
                for (int nt = 0; nt < 4; nt++)
                    s[mt][nt] = __builtin_amdgcn_mfma_f32_16x16x32_bf16(qa[mt][kf], kb[nt], s[mt][nt], 0, 0, 0);
        }

        // fixed-max softmax: p = exp(s), accumulate row sums, repack P -> LDS
#pragma unroll
        for (int mt = 0; mt < 2; mt++)
#pragma unroll
            for (int nt = 0; nt < 4; nt++)
#pragma unroll
                for (int r = 0; r < 4; r++) {
                    float pv = __expf(s[mt][nt][r]);
                    rs[mt][r] += pv;
                    Ps[wave][mt * 16 + lq * 4 + r][nt * 16 + lm] = f2bf(pv);
                }

        // O += P V
#pragma unroll
        for (int kf = 0; kf < 2; kf++) {
            bf16x8 pa[2], vb[4];
#pragma unroll
            for (int mt = 0; mt < 2; mt++)
                pa[mt] = *(const bf16x8*)&Ps[wave][mt * 16 + lm][kf * 32 + lq * 8];
#pragma unroll
            for (int dt = 0; dt < 4; dt++)
                vb[dt] = *(const bf16x8*)&Vs[dt * 16 + lm][kf * 32 + lq * 8];
#pragma unroll
            for (int mt = 0; mt < 2; mt++)
#pragma unroll
                for (int dt = 0; dt < 4; dt++)
                    o[mt][dt] = __builtin_amdgcn_mfma_f32_16x16x32_bf16(pa[mt], vb[dt], o[mt][dt], 0, 0, 0);
        }

        __syncthreads();
        // write prefetched tile to LDS
        if (tile < 15) {
            bf16x8 t0 = {f2bf(kr[0].x), f2bf(kr[0].y), f2bf(kr[0].z), f2bf(kr[0].w),
                         f2bf(kr[1].x), f2bf(kr[1].y), f2bf(kr[1].z), f2bf(kr[1].w)};
            bf16x8 t1 = {f2bf(kr[2].x), f2bf(kr[2].y), f2bf(kr[2].z), f2bf(kr[2].w),
                         f2bf(kr[3].x), f2bf(kr[3].y), f2bf(kr[3].z), f2bf(kr[3].w)};
            *(bf16x8*)&Ks[krow][kcs] = t0;
            *(bf16x8*)&Ks[krow][kcs + 8] = t1;
            int ci0 = tid * 2, ci1 = tid * 2 + 1;
            *(bf16x8*)&Vs[ci0 >> 3][(ci0 & 7) * 8] = vr[0];
            *(bf16x8*)&Vs[ci1 >> 3][(ci1 & 7) * 8] = vr[1];
        }
    }

    // epilogue: reduce l across the 16 lm lanes, O /= l, write obuf[b,p,e] bf16
#pragma unroll
    for (int mt = 0; mt < 2; mt++) {
        float inv[4];
#pragma unroll
        for (int r = 0; r < 4; r++) {
            float t = rs[mt][r];
            t += __shfl_xor(t, 1);
            t += __shfl_xor(t, 2);
            t += __shfl_xor(t, 4);
            t += __shfl_xor(t, 8);
            inv[r] = 1.f / t;
        }
#pragma unroll
        for (int dt = 0; dt < 4; dt++) {
            int e = h * 64 + dt * 16 + lm;
#pragma unroll
            for (int r = 0; r < 4; r++) {
                int p = q0 + wave * 32 + mt * 16 + lq * 4 + r;
                obuf[((size_t)(bb * 1024 + p)) * 1024 + e] = f2bf(o[mt][dt][r] * inv[r]);
            }
        }
    }
}

// ---------------------------------------------------------------------------
// Kernel 4: out = obuf @ out_w^T + out_b  (fp32 out)
// ---------------------------------------------------------------------------
__global__ __launch_bounds__(256) void out_gemm(const short* __restrict__ obuf,
                                                const float* __restrict__ outw,
                                                const float* __restrict__ outb,
                                                float* __restrict__ out) {
    int mblk = blockIdx.x >> 3, nblk = blockIdx.x & 7;
    int m0 = mblk * 128, n0 = nblk * 128;
    __shared__ short As[128][40];
    __shared__ short Bs[128][40];

    int tid = threadIdx.x;
    int srow = tid >> 1, sseg = (tid & 1) * 16;
    const short* ag = obuf + (size_t)(m0 + srow) * 1024 + sseg;
    const float* bg = outw + (size_t)(n0 + srow) * 1024 + sseg;

    int wave = tid >> 6, lane = tid & 63, lm = lane & 15, lq = lane >> 4;
    int wm = (wave >> 1) * 64, wn = (wave & 1) * 64;

    f32x4 acc[4][4];
#pragma unroll
    for (int i = 0; i < 4; i++)
#pragma unroll
        for (int j = 0; j < 4; j++) acc[i][j] = (f32x4){0.f, 0.f, 0.f, 0.f};

    for (int k0 = 0; k0 < 1024; k0 += 32) {
        __syncthreads();
        {
            bf16x8 ta0 = *(const bf16x8*)(ag + k0);
            bf16x8 ta1 = *(const bf16x8*)(ag + k0 + 8);
            float4 b0 = *(const float4*)(bg + k0);
            float4 b1 = *(const float4*)(bg + k0 + 4);
            float4 b2 = *(const float4*)(bg + k0 + 8);
            float4 b3 = *(const float4*)(bg + k0 + 12);
            bf16x8 tb0 = {f2bf(b0.x), f2bf(b0.y), f2bf(b0.z), f2bf(b0.w),
                          f2bf(b1.x), f2bf(b1.y), f2bf(b1.z), f2bf(b1.w)};
            bf16x8 tb1 = {f2bf(b2.x), f2bf(b2.y), f2bf(b2.z), f2bf(b2.w),
                          f2bf(b3.x), f2bf(b3.y), f2bf(b3.z), f2bf(b3.w)};
            *(bf16x8*)&As[srow][sseg] = ta0;
            *(bf16x8*)&As[srow][sseg + 8] = ta1;
            *(bf16x8*)&Bs[srow][sseg] = tb0;
            *(bf16x8*)&Bs[srow][sseg + 8] = tb1;
        }
        __syncthreads();
        bf16x8 af[4], bfr[4];
#pragma unroll
        for (int mt = 0; mt < 4; mt++) af[mt] = *(const bf16x8*)&As[wm + mt * 16 + lm][lq * 8];
#pragma unroll
        for (int nt = 0; nt < 4; nt++) bfr[nt] = *(const bf16x8*)&Bs[wn + nt * 16 + lm][lq * 8];
#pragma unroll
        for (int mt = 0; mt < 4; mt++)
#pragma unroll
            for (int nt = 0; nt < 4; nt++)
                acc[mt][nt] = __builtin_amdgcn_mfma_f32_16x16x32_bf16(af[mt], bfr[nt], acc[mt][nt], 0, 0, 0);
    }

#pragma unroll
    for (int nt = 0; nt < 4; nt++) {
        int e = n0 + wn + nt * 16 + lm;
        float bias = outb[e];
#pragma unroll
        for (int mt = 0; mt < 4; mt++) {
            int pg = m0 + wm + mt * 16 + lq * 4;
#pragma unroll
            for (int r = 0; r < 4; r++)
                out[(size_t)(pg + r) * 1024 + e] = acc[mt][nt][r] + bias;
        }
    }
}

extern "C" void kernel_launch(void* const* d_in, const int* in_sizes, int n_in,
                              void* d_out, int out_size, void* d_ws, size_t ws_size,
                              hipStream_t stream) {
    const float* x    = (const float*)d_in[0];  // [16,1024,1024]
    const float* watt = (const float*)d_in[1];  // [16,64,64]
    const float* bias = (const float*)d_in[2];  // [16,1024,1024]
    const float* wvw  = (const float*)d_in[3];  // [1024,1024]
    const float* wvb  = (const float*)d_in[4];  // [1024]
    const float* outw = (const float*)d_in[5];  // [1024,1024]
    const float* outb = (const float*)d_in[6];  // [1024]
    float* out = (float*)d_out;

    char* ws = (char*)d_ws;
    short* xw    = (short*)ws;                           // 32 MB  [B,H,P,DH] bf16 (Q, pre-scaled)
    short* vt    = (short*)(ws + ((size_t)32 << 20));    // 32 MB  [B,H,DH,P] bf16 (V^T)
    short* obuf  = (short*)(ws + ((size_t)64 << 20));    // 32 MB  [B,P,E]    bf16 (attn out)
    float* biasT = (float*)(ws + ((size_t)96 << 20));    // 64 MB  [H,P,P]    fp32 (bias^T per head)

    bias_prep<<<PH * 32 * 32, 256, 0, stream>>>(bias, biasT);
    xw_kernel<<<PB * PH * 4, 256, 0, stream>>>(x, watt, xw);
    vx_gemm<<<(PB * PP / 128) * (PE / 128), 256, 0, stream>>>(x, wvw, wvb, vt);
    flash_kernel<<<PB * PH * (PP / 128), 256, 0, stream>>>(x, xw, vt, biasT, obuf);
    out_gemm<<<(PB * PP / 128) * (PE / 128), 256, 0, stream>>>(obuf, outw, outb, out);
}

// Round 3
// 470.318 us; speedup vs baseline: 1.8988x; 1.4070x over previous
//
#include <hip/hip_runtime.h>

// Problem constants: B=16, P=1024, E=1024, H=16, DH=64
#define PB 16
#define PP 1024
#define PE 1024
#define PH 16
#define PDH 64

typedef __attribute__((ext_vector_type(8))) short bf16x8;
typedef __attribute__((ext_vector_type(4))) short bf16x4;
typedef __attribute__((ext_vector_type(4))) float f32x4;

__device__ __forceinline__ short f2bf(float f) {
    union { float f; unsigned u; } a;
    a.f = f;
    unsigned u = a.u;
    u += 0x7fffu + ((u >> 16) & 1u);   // round-to-nearest-even
    return (short)(u >> 16);
}
__device__ __forceinline__ float bf2f(short s) {
    union { unsigned u; float f; } a;
    a.u = ((unsigned)(unsigned short)s) << 16;
    return a.f;
}
// async global->LDS, 16B per lane; LDS dest = wave-uniform base + lane*16
__device__ __forceinline__ void async16(const void* g, void* l) {
    __builtin_amdgcn_global_load_lds(
        (const __attribute__((address_space(1))) unsigned int*)g,
        (__attribute__((address_space(3))) unsigned int*)l, 16, 0, 0);
}

// ---------------------------------------------------------------------------
// Kernel 0a: biasTb[h][kv][q] = bf16(bias[h][q][kv])
// ---------------------------------------------------------------------------
__global__ __launch_bounds__(256) void bias_prep(const float* __restrict__ bias,
                                                 short* __restrict__ biasTb) {
    int bid = blockIdx.x;
    int h = bid >> 10;
    int t = bid & 1023;
    int qt = (t >> 5) * 32, kt = (t & 31) * 32;
    __shared__ float tl[32][33];
    int tid = threadIdx.x;
    int r = tid >> 3, c4 = (tid & 7) * 4;
    const float* src = bias + ((size_t)h << 20) + (size_t)(qt + r) * 1024 + kt + c4;
    float4 v = *(const float4*)src;
    tl[r][c4 + 0] = v.x; tl[r][c4 + 1] = v.y; tl[r][c4 + 2] = v.z; tl[r][c4 + 3] = v.w;
    __syncthreads();
    bf16x4 w = {f2bf(tl[c4 + 0][r]), f2bf(tl[c4 + 1][r]), f2bf(tl[c4 + 2][r]), f2bf(tl[c4 + 3][r])};
    *(bf16x4*)(biasTb + ((size_t)h << 20) + (size_t)(kt + r) * 1024 + qt + c4) = w;
}

// ---------------------------------------------------------------------------
// Kernel 0b: weight fp32 -> bf16 (wv_w and out_w, both [n][k] row-major)
// ---------------------------------------------------------------------------
__global__ __launch_bounds__(256) void wconv(const float* __restrict__ wvw,
                                             const float* __restrict__ outw,
                                             short* __restrict__ wvwb,
                                             short* __restrict__ outwb) {
    int bid = blockIdx.x;
    const float* src = (bid < 512) ? wvw : outw;
    short* dst = (bid < 512) ? wvwb : outwb;
    int lb = (bid < 512) ? bid : bid - 512;
    size_t idx = ((size_t)lb * 256 + threadIdx.x) * 8;
    float4 a = *(const float4*)(src + idx);
    float4 b = *(const float4*)(src + idx + 4);
    bf16x8 t = {f2bf(a.x), f2bf(a.y), f2bf(a.z), f2bf(a.w),
                f2bf(b.x), f2bf(b.y), f2bf(b.z), f2bf(b.w)};
    *(bf16x8*)(dst + idx) = t;
}

// ---------------------------------------------------------------------------
// Kernel 1: xw = (x_h @ w_att_val[h]) * 0.125 (bf16)  AND  xbf = bf16(x)
// ---------------------------------------------------------------------------
__global__ __launch_bounds__(256) void xw_kernel(const float* __restrict__ x,
                                                 const float* __restrict__ watt,
                                                 short* __restrict__ xw,
                                                 short* __restrict__ xbf) {
    int bid = blockIdx.x;
    int q4 = bid & 3;
    int bh = bid >> 2;          // b*16 + h
    int h = bh & 15;
    __shared__ short Wt[64][88];   // W^T: Wt[e'][d]

    int tid = threadIdx.x;
    {
        const float* W = watt + (size_t)h * 4096;
        int idx = tid * 16;
        int d = idx >> 6, e0 = idx & 63;
#pragma unroll
        for (int i = 0; i < 16; i += 4) {
            float4 v = *(const float4*)(W + d * 64 + e0 + i);
            Wt[e0 + i + 0][d] = f2bf(v.x);
            Wt[e0 + i + 1][d] = f2bf(v.y);
            Wt[e0 + i + 2][d] = f2bf(v.z);
            Wt[e0 + i + 3][d] = f2bf(v.w);
        }
    }
    __syncthreads();

    int wave = tid >> 6, lane = tid & 63;
    int lm = lane & 15, lq = lane >> 4;

    bf16x8 bfr[4][2];
#pragma unroll
    for (int nt = 0; nt < 4; nt++)
#pragma unroll
        for (int kf = 0; kf < 2; kf++)
            bfr[nt][kf] = *(const bf16x8*)&Wt[nt * 16 + lm][kf * 32 + lq * 8];

    int b = bh >> 4;
    for (int pass = 0; pass < 4; pass++) {
        int p0 = q4 * 256 + pass * 64 + wave * 16;
        const float* xrow = x + ((size_t)(b * 1024 + p0 + lm)) * 1024 + h * 64;
        short* xorow = xbf + ((size_t)(b * 1024 + p0 + lm)) * 1024 + h * 64;
        bf16x8 af[2];
#pragma unroll
        for (int kf = 0; kf < 2; kf++) {
            float4 v0 = *(const float4*)(xrow + kf * 32 + lq * 8);
            float4 v1 = *(const float4*)(xrow + kf * 32 + lq * 8 + 4);
            bf16x8 t;
            t[0] = f2bf(v0.x); t[1] = f2bf(v0.y); t[2] = f2bf(v0.z); t[3] = f2bf(v0.w);
            t[4] = f2bf(v1.x); t[5] = f2bf(v1.y); t[6] = f2bf(v1.z); t[7] = f2bf(v1.w);
            af[kf] = t;
            *(bf16x8*)(xorow + kf * 32 + lq * 8) = t;   // bf16 copy of x
        }
#pragma unroll
        for (int nt = 0; nt < 4; nt++) {
            f32x4 acc = {0.f, 0.f, 0.f, 0.f};
            acc = __builtin_amdgcn_mfma_f32_16x16x32_bf16(af[0], bfr[nt][0], acc, 0, 0, 0);
            acc = __builtin_amdgcn_mfma_f32_16x16x32_bf16(af[1], bfr[nt][1], acc, 0, 0, 0);
            size_t base = ((size_t)bh * 1024 + p0 + lq * 4) * 64 + nt * 16 + lm;
#pragma unroll
            for (int r = 0; r < 4; r++)
                xw[base + (size_t)r * 64] = f2bf(acc[r] * 0.125f);
        }
    }
}

// ---------------------------------------------------------------------------
// Kernel 2: vt[b,h,d,p] = (x @ wv_w^T + wv_b) transposed (bf16).
// m97-style: global_load_lds width-16 into unpadded [128][32] LDS, BK=32.
// ---------------------------------------------------------------------------
__global__ __launch_bounds__(256) void vx_gemm(const short* __restrict__ xbf,
                                               const short* __restrict__ wvwb,
                                               const float* __restrict__ wvb,
                                               short* __restrict__ vt) {
    int mblk = blockIdx.x >> 3, nblk = blockIdx.x & 7;
    int m0 = mblk * 128, n0 = nblk * 128;
    __shared__ short As[128 * 32];
    __shared__ short Bs[128 * 32];

    int tid = threadIdx.x;
    int wv = tid >> 6, ln = tid & 63;
    int c0 = wv * 2;                       // each wave stages chunks c0, c0+1 (16 rows each)
    int rrow = ln >> 2, rseg = (ln & 3) * 8;
    const short* gA = xbf + (size_t)(m0 + c0 * 16 + rrow) * 1024 + rseg;
    const short* gB = wvwb + (size_t)(n0 + c0 * 16 + rrow) * 1024 + rseg;
    short* lA = As + c0 * 512;
    short* lB = Bs + c0 * 512;

    int lane = ln, lm = lane & 15, lq = lane >> 4;
    int wm = (wv >> 1) * 64, wn = (wv & 1) * 64;

    f32x4 acc[4][4];
#pragma unroll
    for (int i = 0; i < 4; i++)
#pragma unroll
        for (int j = 0; j < 4; j++) acc[i][j] = (f32x4){0.f, 0.f, 0.f, 0.f};

    for (int k0 = 0; k0 < 1024; k0 += 32) {
        __syncthreads();
        async16(gA + k0, lA);
        async16(gA + k0 + 16 * 1024, lA + 512);
        async16(gB + k0, lB);
        async16(gB + k0 + 16 * 1024, lB + 512);
        __syncthreads();
        bf16x8 af[4], bfr[4];
#pragma unroll
        for (int mt = 0; mt < 4; mt++) af[mt] = *(const bf16x8*)&As[(wm + mt * 16 + lm) * 32 + lq * 8];
#pragma unroll
        for (int nt = 0; nt < 4; nt++) bfr[nt] = *(const bf16x8*)&Bs[(wn + nt * 16 + lm) * 32 + lq * 8];
#pragma unroll
        for (int mt = 0; mt < 4; mt++)
#pragma unroll
            for (int nt = 0; nt < 4; nt++)
                acc[mt][nt] = __builtin_amdgcn_mfma_f32_16x16x32_bf16(af[mt], bfr[nt], acc[mt][nt], 0, 0, 0);
    }

#pragma unroll
    for (int nt = 0; nt < 4; nt++) {
        int e = n0 + wn + nt * 16 + lm;
        float bias = wvb[e];
        int hh = e >> 6, dd = e & 63;
#pragma unroll
        for (int mt = 0; mt < 4; mt++) {
            int pg = m0 + wm + mt * 16 + lq * 4;
            int bb = pg >> 10, pp = pg & 1023;
            bf16x4 pk;
#pragma unroll
            for (int r = 0; r < 4; r++) pk[r] = f2bf(acc[mt][nt][r] + bias);
            *(bf16x4*)(vt + ((size_t)((bb * 16 + hh) * 64 + dd)) * 1024 + pp) = pk;
        }
    }
}

// ---------------------------------------------------------------------------
// Kernel 3: flash attention v3 — all-bf16 inputs, bias reg-prefetch,
// b-major grid for bias L2 reuse, conflict-free Ps stride.
// ---------------------------------------------------------------------------
__global__ __launch_bounds__(256, 4) void flash_kernel(const short* __restrict__ xbf,
                                                       const short* __restrict__ xw,
                                                       const short* __restrict__ vt,
                                                       const short* __restrict__ biasTb,
                                                       short* __restrict__ obuf) {
    int bid = blockIdx.x;
    int qblk = bid & 7, b = (bid >> 3) & 15, h = bid >> 7;
    int bh = b * 16 + h;
    int q0 = qblk * 128;

    __shared__ short Ks[64][72];       // K[kv][d]
    __shared__ short Vs[64][72];       // V^T[d][kv]
    __shared__ short Ps[4][32][68];    // per-wave P (A layout); 68 -> conflict-free writes

    int tid = threadIdx.x, wave = tid >> 6, lane = tid & 63;
    int lm = lane & 15, lq = lane >> 4;

    // Q A-frags (pre-scaled by 0.125)
    bf16x8 qa[2][2];
#pragma unroll
    for (int mt = 0; mt < 2; mt++)
#pragma unroll
        for (int kf = 0; kf < 2; kf++)
            qa[mt][kf] = *(const bf16x8*)(xw + ((size_t)bh * 1024 + q0 + wave * 32 + mt * 16 + lm) * 64 + kf * 32 + lq * 8);

    f32x4 o[2][4];
#pragma unroll
    for (int mt = 0; mt < 2; mt++)
#pragma unroll
        for (int dt = 0; dt < 4; dt++) o[mt][dt] = (f32x4){0.f, 0.f, 0.f, 0.f};
    float rs[2][4];
#pragma unroll
    for (int mt = 0; mt < 2; mt++)
#pragma unroll
        for (int r = 0; r < 4; r++) rs[mt][r] = 0.f;

    // staging maps: thread stages 2x bf16x8 for K and 2 for V
    int ci0 = tid * 2, ci1 = tid * 2 + 1;
    int r0 = ci0 >> 3, s0 = (ci0 & 7) * 8;
    int r1 = ci1 >> 3, s1 = (ci1 & 7) * 8;
    const short* kg = xbf + ((size_t)(b * 1024)) * 1024 + h * 64;   // + (kv0+row)*1024 + seg
    const short* vg = vt + ((size_t)bh * 64) * 1024;                // + row*1024 + kv0 + seg
    const short* bg = biasTb + ((size_t)h << 20) + q0 + wave * 32;  // + (kv)*1024 + mt*16+lq*4

    bf16x8 kr[2], vr[2];
    bf16x4 br[2][4];
    // prefetch tile 0
    kr[0] = *(const bf16x8*)(kg + (size_t)r0 * 1024 + s0);
    kr[1] = *(const bf16x8*)(kg + (size_t)r1 * 1024 + s1);
    vr[0] = *(const bf16x8*)(vg + (size_t)r0 * 1024 + s0);
    vr[1] = *(const bf16x8*)(vg + (size_t)r1 * 1024 + s1);
#pragma unroll
    for (int mt = 0; mt < 2; mt++)
#pragma unroll
        for (int nt = 0; nt < 4; nt++)
            br[mt][nt] = *(const bf16x4*)(bg + (size_t)(nt * 16 + lm) * 1024 + mt * 16 + lq * 4);
    *(bf16x8*)&Ks[r0][s0] = kr[0];
    *(bf16x8*)&Ks[r1][s1] = kr[1];
    *(bf16x8*)&Vs[r0][s0] = vr[0];
    *(bf16x8*)&Vs[r1][s1] = vr[1];

    for (int tile = 0; tile < 16; tile++) {
        int kv0 = tile * 64;
        __syncthreads();

        // acc init from prefetched bias regs
        f32x4 s[2][4];
#pragma unroll
        for (int mt = 0; mt < 2; mt++)
#pragma unroll
            for (int nt = 0; nt < 4; nt++) {
                bf16x4 bv = br[mt][nt];
                s[mt][nt] = (f32x4){bf2f(bv[0]), bf2f(bv[1]), bf2f(bv[2]), bf2f(bv[3])};
            }

        // prefetch next tile (K, V, bias) into regs — overlaps compute
        if (tile < 15) {
            int kvn = kv0 + 64;
            kr[0] = *(const bf16x8*)(kg + (size_t)(kvn + r0) * 1024 + s0);
            kr[1] = *(const bf16x8*)(kg + (size_t)(kvn + r1) * 1024 + s1);
            vr[0] = *(const bf16x8*)(vg + (size_t)r0 * 1024 + kvn + s0);
            vr[1] = *(const bf16x8*)(vg + (size_t)r1 * 1024 + kvn + s1);
#pragma unroll
            for (int mt = 0; mt < 2; mt++)
#pragma unroll
                for (int nt = 0; nt < 4; nt++)
                    br[mt][nt] = *(const bf16x4*)(bg + (size_t)(kvn + nt * 16 + lm) * 1024 + mt * 16 + lq * 4);
        }

        // S = Q K^T + bias
#pragma unroll
        for (int kf = 0; kf < 2; kf++) {
            bf16x8 kb[4];
#pragma unroll
            for (int nt = 0; nt < 4; nt++)
                kb[nt] = *(const bf16x8*)&Ks[nt * 16 + lm][kf * 32 + lq * 8];
#pragma unroll
            for (int mt = 0; mt < 2; mt++)
#pragma unroll
                for (int nt = 0; nt < 4; nt++)
                    s[mt][nt] = __builtin_amdgcn_mfma_f32_16x16x32_bf16(qa[mt][kf], kb[nt], s[mt][nt], 0, 0, 0);
        }

        // fixed-max softmax, repack P -> LDS (A layout)
#pragma unroll
        for (int mt = 0; mt < 2; mt++)
#pragma unroll
            for (int nt = 0; nt < 4; nt++)
#pragma unroll
                for (int r = 0; r < 4; r++) {
                    float pv = __expf(s[mt][nt][r]);
                    rs[mt][r] += pv;
                    Ps[wave][mt * 16 + lq * 4 + r][nt * 16 + lm] = f2bf(pv);
                }

        // O += P V
#pragma unroll
        for (int kf = 0; kf < 2; kf++) {
            bf16x8 pa[2], vb[4];
#pragma unroll
            for (int mt = 0; mt < 2; mt++)
                pa[mt] = *(const bf16x8*)&Ps[wave][mt * 16 + lm][kf * 32 + lq * 8];
#pragma unroll
            for (int dt = 0; dt < 4; dt++)
                vb[dt] = *(const bf16x8*)&Vs[dt * 16 + lm][kf * 32 + lq * 8];
#pragma unroll
            for (int mt = 0; mt < 2; mt++)
#pragma unroll
                for (int dt = 0; dt < 4; dt++)
                    o[mt][dt] = __builtin_amdgcn_mfma_f32_16x16x32_bf16(pa[mt], vb[dt], o[mt][dt], 0, 0, 0);
        }

        __syncthreads();
        if (tile < 15) {
            *(bf16x8*)&Ks[r0][s0] = kr[0];
            *(bf16x8*)&Ks[r1][s1] = kr[1];
            *(bf16x8*)&Vs[r0][s0] = vr[0];
            *(bf16x8*)&Vs[r1][s1] = vr[1];
        }
    }

    // epilogue
#pragma unroll
    for (int mt = 0; mt < 2; mt++) {
        float inv[4];
#pragma unroll
        for (int r = 0; r < 4; r++) {
            float t = rs[mt][r];
            t += __shfl_xor(t, 1);
            t += __shfl_xor(t, 2);
            t += __shfl_xor(t, 4);
            t += __shfl_xor(t, 8);
            inv[r] = 1.f / t;
        }
#pragma unroll
        for (int dt = 0; dt < 4; dt++) {
            int e = h * 64 + dt * 16 + lm;
#pragma unroll
            for (int r = 0; r < 4; r++) {
                int p = q0 + wave * 32 + mt * 16 + lq * 4 + r;
                obuf[((size_t)(b * 1024 + p)) * 1024 + e] = f2bf(o[mt][dt][r] * inv[r]);
            }
        }
    }
}

// ---------------------------------------------------------------------------
// Kernel 4: out = obuf @ out_w^T + out_b (fp32). m97-style staging.
// ---------------------------------------------------------------------------
__global__ __launch_bounds__(256) void out_gemm(const short* __restrict__ obuf,
                                                const short* __restrict__ outwb,
                                                const float* __restrict__ outb,
                                                float* __restrict__ out) {
    int mblk = blockIdx.x >> 3, nblk = blockIdx.x & 7;
    int m0 = mblk * 128, n0 = nblk * 128;
    __shared__ short As[128 * 32];
    __shared__ short Bs[128 * 32];

    int tid = threadIdx.x;
    int wv = tid >> 6, ln = tid & 63;
    int c0 = wv * 2;
    int rrow = ln >> 2, rseg = (ln & 3) * 8;
    const short* gA = obuf + (size_t)(m0 + c0 * 16 + rrow) * 1024 + rseg;
    const short* gB = outwb + (size_t)(n0 + c0 * 16 + rrow) * 1024 + rseg;
    short* lA = As + c0 * 512;
    short* lB = Bs + c0 * 512;

    int lm = ln & 15, lq = ln >> 4;
    int wm = (wv >> 1) * 64, wn = (wv & 1) * 64;

    f32x4 acc[4][4];
#pragma unroll
    for (int i = 0; i < 4; i++)
#pragma unroll
        for (int j = 0; j < 4; j++) acc[i][j] = (f32x4){0.f, 0.f, 0.f, 0.f};

    for (int k0 = 0; k0 < 1024; k0 += 32) {
        __syncthreads();
        async16(gA + k0, lA);
        async16(gA + k0 + 16 * 1024, lA + 512);
        async16(gB + k0, lB);
        async16(gB + k0 + 16 * 1024, lB + 512);
        __syncthreads();
        bf16x8 af[4], bfr[4];
#pragma unroll
        for (int mt = 0; mt < 4; mt++) af[mt] = *(const bf16x8*)&As[(wm + mt * 16 + lm) * 32 + lq * 8];
#pragma unroll
        for (int nt = 0; nt < 4; nt++) bfr[nt] = *(const bf16x8*)&Bs[(wn + nt * 16 + lm) * 32 + lq * 8];
#pragma unroll
        for (int mt = 0; mt < 4; mt++)
#pragma unroll
            for (int nt = 0; nt < 4; nt++)
                acc[mt][nt] = __builtin_amdgcn_mfma_f32_16x16x32_bf16(af[mt], bfr[nt], acc[mt][nt], 0, 0, 0);
    }

#pragma unroll
    for (int nt = 0; nt < 4; nt++) {
        int e = n0 + wn + nt * 16 + lm;
        float bias = outb[e];
#pragma unroll
        for (int mt = 0; mt < 4; mt++) {
            int pg = m0 + wm + mt * 16 + lq * 4;
#pragma unroll
            for (int r = 0; r < 4; r++)
                out[(size_t)(pg + r) * 1024 + e] = acc[mt][nt][r] + bias;
        }
    }
}

extern "C" void kernel_launch(void* const* d_in, const int* in_sizes, int n_in,
                              void* d_out, int out_size, void* d_ws, size_t ws_size,
                              hipStream_t stream) {
    const float* x    = (const float*)d_in[0];  // [16,1024,1024]
    const float* watt = (const float*)d_in[1];  // [16,64,64]
    const float* bias = (const float*)d_in[2];  // [16,1024,1024]
    const float* wvw  = (const float*)d_in[3];  // [1024,1024]
    const float* wvb  = (const float*)d_in[4];  // [1024]
    const float* outw = (const float*)d_in[5];  // [1024,1024]
    const float* outb = (const float*)d_in[6];  // [1024]
    float* out = (float*)d_out;

    char* ws = (char*)d_ws;
    short* xw     = (short*)ws;                           // 32 MB  [B,H,P,DH] bf16 (Q, pre-scaled)
    short* vt     = (short*)(ws + ((size_t)32 << 20));    // 32 MB  [B,H,DH,P] bf16 (V^T)
    short* obuf   = (short*)(ws + ((size_t)64 << 20));    // 32 MB  [B,P,E]    bf16 (attn out)
    short* biasTb = (short*)(ws + ((size_t)96 << 20));    // 32 MB  [H,P,P]    bf16 (bias^T)
    short* xbf    = (short*)(ws + ((size_t)128 << 20));   // 32 MB  [B,P,E]    bf16 (x)
    short* wvwb   = (short*)(ws + ((size_t)160 << 20));   // 2 MB
    short* outwb  = (short*)(ws + ((size_t)162 << 20));   // 2 MB

    xw_kernel<<<PB * PH * 4, 256, 0, stream>>>(x, watt, xw, xbf);
    bias_prep<<<PH * 32 * 32, 256, 0, stream>>>(bias, biasTb);
    wconv<<<1024, 256, 0, stream>>>(wvw, outw, wvwb, outwb);
    vx_gemm<<<(PB * PP / 128) * (PE / 128), 256, 0, stream>>>(xbf, wvwb, wvb, vt);
    flash_kernel<<<PB * PH * (PP / 128), 256, 0, stream>>>(xbf, xw, vt, biasTb, obuf);
    out_gemm<<<(PB * PP / 128) * (PE / 128), 256, 0, stream>>>(obuf, outwb, outb, out);
}